// Round 1
// baseline (18730.087 us; speedup 1.0000x reference)
//
#include <hip/hip_runtime.h>
#include <hip/hip_bf16.h>
#include <stdint.h>

typedef unsigned short u16;
typedef __attribute__((ext_vector_type(8))) short short8;
typedef __attribute__((ext_vector_type(4))) float f32x4;

#define B_   128
#define TL_  400
#define AL_  50
#define QL_  32
#define E_   300
#define H3_  900
#define V_   30000
#define EP_  320     // E padded (K for gi GEMM)
#define K2P_ 640     // 2H padded (K for qproj GEMM, text_rep stride)
#define KDP_ 1216    // 1200 padded (K for dec + out GEMM)
#define NDP_ 1920    // 1800 padded (dec gi+gh cols)
#define MT_  51200   // B*TL
#define MA_  6400    // B*AL
#define MD_  3968    // 31*128

static __device__ __forceinline__ float bf2f(u16 u) {
    union { float f; unsigned v; } c; c.v = ((unsigned)u) << 16; return c.f;
}
static __device__ __forceinline__ u16 f2bf(float f) {
    union { float f; unsigned v; } c; c.f = f;
    unsigned r = c.v + 0x7FFF + ((c.v >> 16) & 1);
    return (u16)(r >> 16);
}
static __device__ __forceinline__ float sigm(float x) { return 1.f / (1.f + __expf(-x)); }

// ---------------------------------------------------------------- transpose+convert
// dst[(n0+n)*ldbt + k0 + k] = bf16(src[k*N + n])   (pads stay memset-zero)
__global__ __launch_bounds__(256) void transpose_cvt(const float* __restrict__ src, int K, int N,
                                                     u16* __restrict__ dst, int ldbt, int n0, int k0) {
    __shared__ float tile[32][33];
    int kb = blockIdx.x * 32, nb = blockIdx.y * 32;
    int tx = threadIdx.x & 31, ty = threadIdx.x >> 5;   // 32x8
    for (int i = ty; i < 32; i += 8) {
        int k = kb + i, n = nb + tx;
        tile[i][tx] = (k < K && n < N) ? src[(size_t)k * N + n] : 0.f;
    }
    __syncthreads();
    for (int i = ty; i < 32; i += 8) {
        int n = nb + i, k = kb + tx;
        if (n < N && k < K) dst[(size_t)(n0 + n) * ldbt + k0 + k] = f2bf(tile[tx][i]);
    }
}

__global__ __launch_bounds__(256) void build_dec_bias(const float* __restrict__ bih,
                                                      const float* __restrict__ bhh,
                                                      float* __restrict__ bias) {
    int i = blockIdx.x * 256 + threadIdx.x;
    if (i < 900) bias[i] = bih[i];
    else if (i < 1800) bias[i] = bhh[i - 900];
    else if (i < NDP_) bias[i] = 0.f;
}

// ---------------------------------------------------------------- embedding gathers
__global__ __launch_bounds__(256) void gather_rows(const int* __restrict__ idx, const float* __restrict__ emb,
                                                   u16* __restrict__ dst, int ldd) {
    int r = blockIdx.x;
    int id = idx[r];
    const float* e = emb + (size_t)id * E_;
    for (int i = threadIdx.x; i < E_; i += 256) dst[(size_t)r * ldd + i] = f2bf(e[i]);
}

// question -> A_dec[t][b][0:300] and A_out[t*128+b][900:1200]
__global__ __launch_bounds__(256) void gather_q(const int* __restrict__ question, const float* __restrict__ emb,
                                                u16* __restrict__ A_dec, u16* __restrict__ A_out) {
    int r = blockIdx.x;            // t*128 + b,  r < 3968
    int t = r >> 7, b = r & 127;
    int id = question[b * QL_ + t];
    const float* e = emb + (size_t)id * E_;
    for (int i = threadIdx.x; i < E_; i += 256) {
        u16 u = f2bf(e[i]);
        A_dec[(size_t)r * KDP_ + i] = u;
        A_out[(size_t)r * KDP_ + 900 + i] = u;
    }
}

// ---------------------------------------------------------------- bf16 MFMA GEMM, C = A * Bt^T
// A row-major [M, lda] bf16, Bt row-major [Npad, ldb] bf16 (Bt[n][k] = B[k][n]).
// M % 128 == 0, Kpad % 32 == 0, lda/ldb % 8 == 0, Npad covered by gridDim.x*128 (zero-padded).
// MODE 0: f32 store C[row*ldc+col];  1: bf16 store;  2: logits f32 store with (t,b) row remap.
template <int MODE>
__global__ __launch_bounds__(256) void gemm_bt(const u16* __restrict__ A, int lda,
                                               const u16* __restrict__ Bt, int ldb,
                                               void* __restrict__ Cv, int ldc, int Nreal,
                                               const float* __restrict__ bias, int Kpad) {
    __shared__ u16 lA[128 * 32];
    __shared__ u16 lB[128 * 32];
    const int tid = threadIdx.x;
    const int bn = blockIdx.x, bm = blockIdx.y;
    const long row0 = (long)bm * 128;
    const u16* Ab = A + row0 * lda;
    const u16* Bb = Bt + (long)bn * 128 * ldb;
    const int lane = tid & 63, wave = tid >> 6;
    const int wr = wave >> 1, wc = wave & 1;
    const int lr = lane & 15, ko = (lane >> 4) * 8;
    f32x4 acc[4][4] = {};

    for (int k0 = 0; k0 < Kpad; k0 += 32) {
#pragma unroll
        for (int i = 0; i < 2; ++i) {
            const int c = tid + 256 * i;
            const int e = c * 8;                    // ushort index in the 128x32 tile
            const int r = e >> 5, col = e & 31;
            __builtin_amdgcn_global_load_lds(
                (const __attribute__((address_space(1))) void*)(Ab + (long)r * lda + k0 + col),
                (__attribute__((address_space(3))) void*)(&lA[e]), 16, 0, 0);
            __builtin_amdgcn_global_load_lds(
                (const __attribute__((address_space(1))) void*)(Bb + (long)r * ldb + k0 + col),
                (__attribute__((address_space(3))) void*)(&lB[e]), 16, 0, 0);
        }
        __syncthreads();
        short8 af[4], bfr[4];
#pragma unroll
        for (int i = 0; i < 4; ++i) {
            af[i]  = *(const short8*)&lA[(wr * 64 + i * 16 + lr) * 32 + ko];
            bfr[i] = *(const short8*)&lB[(wc * 64 + i * 16 + lr) * 32 + ko];
        }
#pragma unroll
        for (int i = 0; i < 4; ++i)
#pragma unroll
            for (int j = 0; j < 4; ++j)
                acc[i][j] = __builtin_amdgcn_mfma_f32_16x16x32_bf16(af[i], bfr[j], acc[i][j], 0, 0, 0);
        __syncthreads();
    }

    const int r4 = (lane >> 4) * 4;
    const int cl = lane & 15;
#pragma unroll
    for (int i = 0; i < 4; ++i) {
#pragma unroll
        for (int j = 0; j < 4; ++j) {
            const int colg = bn * 128 + wc * 64 + j * 16 + cl;
            if (colg >= Nreal) continue;
            const float bv = bias ? bias[colg] : 0.f;
#pragma unroll
            for (int v = 0; v < 4; ++v) {
                const long rowg = row0 + wr * 64 + i * 16 + r4 + v;
                const float val = acc[i][j][v] + bv;
                if (MODE == 0) {
                    ((float*)Cv)[rowg * (long)ldc + colg] = val;
                } else if (MODE == 1) {
                    ((u16*)Cv)[rowg * (long)ldc + colg] = f2bf(val);
                } else {
                    const int tt = (int)(rowg >> 7), bb = (int)(rowg & 127);
                    ((float*)Cv)[((long)bb * QL_ + tt + 1) * (long)V_ + colg] = val;
                }
            }
        }
    }
}

// ---------------------------------------------------------------- encoder recurrent step
// tasks: 0 text-fwd, 1 text-bwd, 2 ans-fwd (t<50), 3 ans-bwd (t==0 only; processes x[49])
// h_enc layout: [parity 2][task 4][128][300] f32
__global__ __launch_bounds__(256) void enc_step(int t,
        const float* __restrict__ Whh_tf, const float* __restrict__ Whh_tb,
        const float* __restrict__ Whh_af, const float* __restrict__ Whh_ab,
        const float* __restrict__ bhh_tf, const float* __restrict__ bhh_tb,
        const float* __restrict__ bhh_af, const float* __restrict__ bhh_ab,
        const u16* __restrict__ gi_tf, const u16* __restrict__ gi_tb,
        const u16* __restrict__ gi_af, const u16* __restrict__ gi_ab,
        float* __restrict__ h_enc, u16* __restrict__ text_rep) {
    const int blk = blockIdx.x;
    const int task = blk / 80;
    const int bg = (blk % 80) / 5;
    const int jc = blk % 5;
    if (task == 2 && t >= AL_) return;
    if (task == 3 && t != 0) return;
    const float* Whh; const float* bhh; const u16* gi; int T;
    if (task == 0)      { Whh = Whh_tf; bhh = bhh_tf; gi = gi_tf; T = TL_; }
    else if (task == 1) { Whh = Whh_tb; bhh = bhh_tb; gi = gi_tb; T = TL_; }
    else if (task == 2) { Whh = Whh_af; bhh = bhh_af; gi = gi_af; T = AL_; }
    else                { Whh = Whh_ab; bhh = bhh_ab; gi = gi_ab; T = AL_; }
    const int t_eff = (task == 1 || task == 3) ? (T - 1 - t) : t;

    __shared__ float hs[8 * 300];
    const float* h_cur = h_enc + (size_t)(((t & 1) * 4 + task) * 128 + bg * 8) * 300;
    float* h_nxt = h_enc + (size_t)((((t + 1) & 1) * 4 + task) * 128) * 300;
    const int tid = threadIdx.x;
    for (int i = tid; i < 2400; i += 256) hs[i] = h_cur[i];
    __syncthreads();

    const int j = jc * 64 + (tid & 63);
    if (j >= 300) return;
    const int bs = tid >> 6;
    float a0r = 0, a0z = 0, a0n = 0, a1r = 0, a1z = 0, a1n = 0;
    for (int k = 0; k < 300; ++k) {
        const float* wrow = Whh + k * 900;
        const float w0 = wrow[j], w1 = wrow[j + 300], w2 = wrow[j + 600];
        const float h0 = hs[bs * 300 + k], h1 = hs[(bs + 4) * 300 + k];
        a0r += h0 * w0; a0z += h0 * w1; a0n += h0 * w2;
        a1r += h1 * w0; a1z += h1 * w1; a1n += h1 * w2;
    }
    const float br = bhh[j], bz = bhh[j + 300], bnn = bhh[j + 600];
#pragma unroll
    for (int half = 0; half < 2; ++half) {
        const int bl = bs + half * 4;
        const int b = bg * 8 + bl;
        const float gr_ = half ? a1r : a0r, gz_ = half ? a1z : a0z, gn_ = half ? a1n : a0n;
        const size_t gidx = ((size_t)b * T + t_eff) * 900;   // gi already has +bih (GEMM bias)
        const float gir = bf2f(gi[gidx + j]);
        const float giz = bf2f(gi[gidx + j + 300]);
        const float gin = bf2f(gi[gidx + j + 600]);
        const float r = sigm(gir + gr_ + br);
        const float z = sigm(giz + gz_ + bz);
        const float n = tanhf(gin + r * (gn_ + bnn));
        const float hp = hs[bl * 300 + j];
        const float hn = (1.f - z) * n + z * hp;
        h_nxt[(size_t)b * 300 + j] = hn;
        if (task < 2) text_rep[((size_t)b * TL_ + t_eff) * K2P_ + task * 300 + j] = f2bf(hn);
    }
}

// ---------------------------------------------------------------- hidden0 = ans_rep[:,-1,:] @ trans_W + trans_b
__global__ __launch_bounds__(256) void trans_hidden(const float* __restrict__ h_enc,
                                                    const float* __restrict__ trans_W,
                                                    const float* __restrict__ trans_b,
                                                    float* __restrict__ h_dec, u16* __restrict__ A_dec0) {
    int b = blockIdx.x, tid = threadIdx.x;
    __shared__ float si[600];
    const float* af = h_enc + (size_t)((0 * 4 + 2) * 128 + b) * 300;  // ans-fwd final (parity 0)
    const float* ab = h_enc + (size_t)((1 * 4 + 3) * 128 + b) * 300;  // ans-bwd (written at t=0 -> parity 1)
    for (int i = tid; i < 300; i += 256) { si[i] = af[i]; si[300 + i] = ab[i]; }
    __syncthreads();
    for (int jj = tid; jj < 300; jj += 256) {
        float acc = trans_b[jj];
        for (int k = 0; k < 600; ++k) acc += si[k] * trans_W[k * 300 + jj];
        h_dec[(size_t)b * 300 + jj] = acc;
        A_dec0[(size_t)b * KDP_ + 900 + jj] = f2bf(acc);
    }
}

// ---------------------------------------------------------------- attention (one block per batch row)
__global__ __launch_bounds__(256) void attn_step(int t, const float* __restrict__ h_dec,
                                                 const float* __restrict__ Wk, const float* __restrict__ av,
                                                 const float* __restrict__ qproj, const u16* __restrict__ text_rep,
                                                 u16* __restrict__ A_dec_t, u16* __restrict__ A_out) {
    const int b = blockIdx.x, tid = threadIdx.x, lane = tid & 63, wave = tid >> 6;
    __shared__ float sh[300], hwk[300], sc[400], red[8];
    for (int i = tid; i < 300; i += 256) sh[i] = h_dec[(size_t)b * 300 + i];
    __syncthreads();
    for (int jj = tid; jj < 300; jj += 256) {
        float acc = 0.f;
        for (int k = 0; k < 300; ++k) acc += sh[k] * Wk[k * 300 + jj];
        hwk[jj] = acc;
    }
    __syncthreads();
    for (int s = wave; s < 400; s += 4) {
        const float* qp = qproj + ((size_t)b * TL_ + s) * 300;
        float p = 0.f;
        for (int d = lane; d < 300; d += 64) {
            float e = qp[d] + hwk[d];
            e = fminf(fmaxf(e, -15.f), 15.f);
            float ex = __expf(2.f * e);
            p += ((ex - 1.f) / (ex + 1.f)) * av[d];
        }
#pragma unroll
        for (int off = 32; off > 0; off >>= 1) p += __shfl_down(p, off);
        if (lane == 0) sc[s] = p;
    }
    __syncthreads();
    float m = -1e30f;
    for (int i = tid; i < 400; i += 256) m = fmaxf(m, sc[i]);
#pragma unroll
    for (int off = 32; off > 0; off >>= 1) m = fmaxf(m, __shfl_down(m, off));
    if (lane == 0) red[wave] = m;
    __syncthreads();
    m = fmaxf(fmaxf(red[0], red[1]), fmaxf(red[2], red[3]));
    float ssum = 0.f;
    for (int i = tid; i < 400; i += 256) { float e = __expf(sc[i] - m); sc[i] = e; ssum += e; }
#pragma unroll
    for (int off = 32; off > 0; off >>= 1) ssum += __shfl_down(ssum, off);
    if (lane == 0) red[4 + wave] = ssum;
    __syncthreads();
    const float inv = 1.f / (red[4] + red[5] + red[6] + red[7]);
    for (int e0 = tid; e0 < 600; e0 += 256) {
        float acc = 0.f;
        for (int s = 0; s < 400; ++s) acc += sc[s] * bf2f(text_rep[((size_t)b * TL_ + s) * K2P_ + e0]);
        u16 wv = f2bf(acc * inv);
        A_dec_t[(size_t)b * KDP_ + 300 + e0] = wv;
        A_out[((size_t)t * 128 + b) * KDP_ + 300 + e0] = wv;
    }
}

// ---------------------------------------------------------------- decoder GRU gates
__global__ __launch_bounds__(256) void dec_gate(int t, const float* __restrict__ g_all,
                                                float* __restrict__ h_dec,
                                                u16* __restrict__ A_dec, u16* __restrict__ A_out) {
    int idx = blockIdx.x * 256 + threadIdx.x;
    if (idx >= 128 * 300) return;
    int b = idx / 300, j = idx % 300;
    const float* g = g_all + (size_t)b * NDP_;
    float r = sigm(g[j] + g[900 + j]);
    float z = sigm(g[300 + j] + g[1200 + j]);
    float n = tanhf(g[600 + j] + r * g[1500 + j]);
    float hp = h_dec[idx];
    float hn = (1.f - z) * n + z * hp;
    h_dec[idx] = hn;
    u16 u = f2bf(hn);
    A_out[((size_t)t * 128 + b) * KDP_ + j] = u;
    if (t < 30) A_dec[((size_t)(t + 1) * 128 + b) * KDP_ + 900 + j] = u;
}

__global__ __launch_bounds__(256) void zero_t0(float* __restrict__ out) {
    int i = blockIdx.x * 256 + threadIdx.x;
    if (i < 128 * V_) {
        int b = i / V_, v = i % V_;
        out[(size_t)b * QL_ * V_ + v] = 0.f;
    }
}

// ================================================================ host
extern "C" void kernel_launch(void* const* d_in, const int* in_sizes, int n_in,
                              void* d_out, int out_size, void* d_ws, size_t ws_size,
                              hipStream_t stream) {
    (void)in_sizes; (void)n_in; (void)out_size;
    const int*   text      = (const int*)d_in[0];
    const int*   answer    = (const int*)d_in[1];
    const int*   question  = (const int*)d_in[2];
    const float* embedding = (const float*)d_in[3];
    const float* te_Wih_f = (const float*)d_in[4],  *te_Whh_f = (const float*)d_in[5];
    const float* te_bih_f = (const float*)d_in[6],  *te_bhh_f = (const float*)d_in[7];
    const float* te_Wih_b = (const float*)d_in[8],  *te_Whh_b = (const float*)d_in[9];
    const float* te_bih_b = (const float*)d_in[10], *te_bhh_b = (const float*)d_in[11];
    const float* ae_Wih_f = (const float*)d_in[12], *ae_Whh_f = (const float*)d_in[13];
    const float* ae_bih_f = (const float*)d_in[14], *ae_bhh_f = (const float*)d_in[15];
    const float* ae_Wih_b = (const float*)d_in[16], *ae_Whh_b = (const float*)d_in[17];
    const float* ae_bih_b = (const float*)d_in[18], *ae_bhh_b = (const float*)d_in[19];
    const float* trans_W  = (const float*)d_in[20], *trans_b  = (const float*)d_in[21];
    const float* attn_Wk  = (const float*)d_in[22], *attn_Wq  = (const float*)d_in[23];
    const float* attn_b   = (const float*)d_in[24], *attn_v   = (const float*)d_in[25];
    const float* dec_Wih  = (const float*)d_in[26], *dec_Whh  = (const float*)d_in[27];
    const float* dec_bih  = (const float*)d_in[28], *dec_bhh  = (const float*)d_in[29];
    const float* out_W    = (const float*)d_in[30], *out_b    = (const float*)d_in[31];
    float* out = (float*)d_out;

    // ---- workspace carve (all sizes already 256B-aligned)
    char* w = (char*)d_ws; size_t off = 0;
    auto alloc = [&](size_t bytes) -> void* { void* p = w + off; off += (bytes + 255) & ~(size_t)255; return p; };
    u16* WihT_tf = (u16*)alloc(1024 * EP_ * 2);
    u16* WihT_tb = (u16*)alloc(1024 * EP_ * 2);
    u16* WihT_af = (u16*)alloc(1024 * EP_ * 2);
    u16* WihT_ab = (u16*)alloc(1024 * EP_ * 2);
    u16* WqT     = (u16*)alloc(384 * K2P_ * 2);
    u16* outWT   = (u16*)alloc((size_t)30080 * KDP_ * 2);
    u16* decBT   = (u16*)alloc((size_t)NDP_ * KDP_ * 2);
    float* decBias = (float*)alloc(NDP_ * 4);
    u16* textEmb = (u16*)alloc((size_t)MT_ * EP_ * 2);
    u16* ansEmb  = (u16*)alloc((size_t)MA_ * EP_ * 2);
    u16* gi_tf   = (u16*)alloc((size_t)MT_ * 900 * 2);
    u16* gi_tb   = (u16*)alloc((size_t)MT_ * 900 * 2);
    u16* gi_af   = (u16*)alloc((size_t)MA_ * 900 * 2);
    u16* gi_ab   = (u16*)alloc((size_t)MA_ * 900 * 2);
    u16* text_rep = (u16*)alloc((size_t)MT_ * K2P_ * 2);
    float* qproj = (float*)alloc((size_t)MT_ * 300 * 4);
    float* h_enc = (float*)alloc((size_t)2 * 4 * 128 * 300 * 4);
    float* h_dec = (float*)alloc((size_t)128 * 300 * 4);
    u16* A_dec   = (u16*)alloc((size_t)MD_ * KDP_ * 2);
    u16* A_out   = (u16*)alloc((size_t)MD_ * KDP_ * 2);
    float* gi_gh = (float*)alloc((size_t)128 * NDP_ * 4);
    const size_t need = off;
    size_t zbytes = need <= ws_size ? need : ws_size;

    // zero all staging (pads must be 0; h0 = 0; ws is poisoned before timing)
    hipMemsetAsync(d_ws, 0, zbytes, stream);

    // ---- weight conversion / transposition
    transpose_cvt<<<dim3(10, 29), 256, 0, stream>>>(te_Wih_f, 300, 900, WihT_tf, EP_, 0, 0);
    transpose_cvt<<<dim3(10, 29), 256, 0, stream>>>(te_Wih_b, 300, 900, WihT_tb, EP_, 0, 0);
    transpose_cvt<<<dim3(10, 29), 256, 0, stream>>>(ae_Wih_f, 300, 900, WihT_af, EP_, 0, 0);
    transpose_cvt<<<dim3(10, 29), 256, 0, stream>>>(ae_Wih_b, 300, 900, WihT_ab, EP_, 0, 0);
    transpose_cvt<<<dim3(19, 10), 256, 0, stream>>>(attn_Wq, 600, 300, WqT, K2P_, 0, 0);
    transpose_cvt<<<dim3(38, 938), 256, 0, stream>>>(out_W, 1200, V_, outWT, KDP_, 0, 0);
    transpose_cvt<<<dim3(29, 29), 256, 0, stream>>>(dec_Wih, 900, 900, decBT, KDP_, 0, 0);
    transpose_cvt<<<dim3(10, 29), 256, 0, stream>>>(dec_Whh, 300, 900, decBT, KDP_, 900, 900);
    build_dec_bias<<<8, 256, 0, stream>>>(dec_bih, dec_bhh, decBias);

    // ---- embedding gathers
    gather_rows<<<MT_, 256, 0, stream>>>(text, embedding, textEmb, EP_);
    gather_rows<<<MA_, 256, 0, stream>>>(answer, embedding, ansEmb, EP_);
    gather_q<<<MD_, 256, 0, stream>>>(question, embedding, A_dec, A_out);

    // ---- gi = x @ Wih + bih  (bf16 MFMA GEMMs)
    gemm_bt<1><<<dim3(8, 400), 256, 0, stream>>>(textEmb, EP_, WihT_tf, EP_, gi_tf, 900, 900, te_bih_f, EP_);
    gemm_bt<1><<<dim3(8, 400), 256, 0, stream>>>(textEmb, EP_, WihT_tb, EP_, gi_tb, 900, 900, te_bih_b, EP_);
    gemm_bt<1><<<dim3(8, 50),  256, 0, stream>>>(ansEmb, EP_, WihT_af, EP_, gi_af, 900, 900, ae_bih_f, EP_);
    gemm_bt<1><<<dim3(8, 50),  256, 0, stream>>>(ansEmb, EP_, WihT_ab, EP_, gi_ab, 900, 900, ae_bih_b, EP_);

    // ---- encoder recurrences (text fwd+bwd 400 steps; ans fwd 50; ans bwd 1 step at t=0)
    for (int t = 0; t < TL_; ++t)
        enc_step<<<320, 256, 0, stream>>>(t, te_Whh_f, te_Whh_b, ae_Whh_f, ae_Whh_b,
                                          te_bhh_f, te_bhh_b, ae_bhh_f, ae_bhh_b,
                                          gi_tf, gi_tb, gi_af, gi_ab, h_enc, text_rep);

    // ---- decoder init + qproj
    trans_hidden<<<128, 256, 0, stream>>>(h_enc, trans_W, trans_b, h_dec, A_dec);
    gemm_bt<0><<<dim3(3, 400), 256, 0, stream>>>(text_rep, K2P_, WqT, K2P_, qproj, 300, 300, attn_b, K2P_);

    // ---- decode loop
    for (int t = 0; t < QL_ - 1; ++t) {
        attn_step<<<128, 256, 0, stream>>>(t, h_dec, attn_Wk, attn_v, qproj, text_rep,
                                           A_dec + (size_t)t * 128 * KDP_, A_out);
        gemm_bt<0><<<dim3(15, 1), 256, 0, stream>>>(A_dec + (size_t)t * 128 * KDP_, KDP_,
                                                    decBT, KDP_, gi_gh, NDP_, 1800, decBias, KDP_);
        dec_gate<<<150, 256, 0, stream>>>(t, gi_gh, h_dec, A_dec, A_out);
    }

    // ---- logits: [h_new | weighted | emb] @ out_W + out_b  -> d_out[:, 1:, :]
    gemm_bt<2><<<dim3(235, 31), 256, 0, stream>>>(A_out, KDP_, outWT, KDP_, d_out, 0, V_, out_b, KDP_);
    zero_t0<<<(128 * V_ + 255) / 256, 256, 0, stream>>>(out);
}